// Round 1
// baseline (1318.446 us; speedup 1.0000x reference)
//
#include <hip/hip_runtime.h>
#include <hip/hip_bf16.h>

// Problem constants
#define QN 1024
#define NDB 200000
#define PDBW 257
#define CDIM 256
#define MT 128            // queries per block (stage 1)
#define NT 128            // db rows per subtile
#define SUBT 32           // subtiles per chunk
#define CHUNK (NT*SUBT)   // 4096 db rows per chunk
#define NCHUNK 49         // ceil(200000/4096)
#define TK 16
#define CAND_PER_Q (NCHUNK*32)   // 1568 candidates per query
#define NEGF (-1e30f)
#define MIN_SIM_C 0.05f
#define MIN_VOTES_C 0.3f

typedef __attribute__((ext_vector_type(8))) short bf16x8;
typedef __attribute__((ext_vector_type(4))) float f32x4;

__device__ __forceinline__ short f2bf(float f) {
  union { float f; unsigned u; } x; x.f = f;
  unsigned u = x.u;
  return (short)((u + 0x7fffu + ((u >> 16) & 1u)) >> 16);  // RNE
}

// ---------------------------------------------------------------------------
// Stage 1: bf16 MFMA sims + fused per-chunk top-16
// grid (NCHUNK, 8), block 256 (4 waves). Wave w computes 32 queries x 128 db.
// LDS: db tile [128][264] bf16 (padded) reused as sims [128][129] f32.
// ---------------------------------------------------------------------------
__global__ __launch_bounds__(256, 2) void sims_topk_kernel(
    const float* __restrict__ qd, const float* __restrict__ pdb,
    float* __restrict__ cand_val, unsigned int* __restrict__ cand_idx)
{
  __shared__ __align__(16) short db_lds[128 * 264];
  float* sims = (float*)db_lds;  // [128][129] overlay (66048B <= 67584B)

  const int tid  = (int)threadIdx.x;
  const int lane = tid & 63;
  const int wv   = tid >> 6;
  const int cid   = (int)blockIdx.x;   // chunk id
  const int mtile = (int)blockIdx.y;   // query tile

  // ---- preload Q fragments (bf16) for this wave's 32 query rows, K=256 ----
  bf16x8 aq[2][8];
  {
    const int l15 = lane & 15;
    const int kb  = (lane >> 4) << 3;
    #pragma unroll
    for (int fm = 0; fm < 2; ++fm) {
      const int row = mtile*MT + wv*32 + fm*16 + l15;
      #pragma unroll
      for (int kk = 0; kk < 8; ++kk) {
        const float* p = qd + (size_t)row*CDIM + kk*32 + kb;
        float4 x0 = *(const float4*)p;
        float4 x1 = *(const float4*)(p + 4);
        bf16x8 a;
        a[0]=f2bf(x0.x); a[1]=f2bf(x0.y); a[2]=f2bf(x0.z); a[3]=f2bf(x0.w);
        a[4]=f2bf(x1.x); a[5]=f2bf(x1.y); a[6]=f2bf(x1.z); a[7]=f2bf(x1.w);
        aq[fm][kk] = a;
      }
    }
  }

  // per-thread top-16 list (unordered, tracked min) for (query q_l, half)
  float    tv[TK];
  unsigned ti[TK];
  #pragma unroll
  for (int i = 0; i < TK; ++i) { tv[i] = NEGF; ti[i] = 0u; }
  float minv = NEGF; int minp = 0;

  const int g0chunk = cid * CHUNK;
  const int q_l  = tid & 127;
  const int half = tid >> 7;

  for (int s = 0; s < SUBT; ++s) {
    const int g0 = g0chunk + s*NT;

    // ---- stage db rows [g0, g0+128) fp32 -> bf16 LDS ----
    {
      const int rb = tid >> 6;          // 0..3
      const int c4 = (tid & 63) << 2;   // 0..252
      for (int i = 0; i < 32; ++i) {
        const int rl = i*4 + rb;
        const int g  = g0 + rl;
        float v0, v1, v2, v3;
        if (g < NDB) {
          const float* p = pdb + (size_t)g*PDBW + c4;
          v0 = p[0]; v1 = p[1]; v2 = p[2]; v3 = p[3];
        } else { v0 = v1 = v2 = v3 = 0.f; }
        short* d = &db_lds[rl*264 + c4];
        d[0]=f2bf(v0); d[1]=f2bf(v1); d[2]=f2bf(v2); d[3]=f2bf(v3);
      }
    }
    __syncthreads();

    // ---- MFMA: this wave's 32q x 128db over K=256 ----
    f32x4 acc[2][8];
    #pragma unroll
    for (int fm = 0; fm < 2; ++fm)
      #pragma unroll
      for (int fn = 0; fn < 8; ++fn)
        acc[fm][fn] = (f32x4){0.f, 0.f, 0.f, 0.f};
    {
      const int l15 = lane & 15;
      const int kb  = (lane >> 4) << 3;
      #pragma unroll
      for (int kk = 0; kk < 8; ++kk) {
        bf16x8 b[8];
        #pragma unroll
        for (int fn = 0; fn < 8; ++fn)
          b[fn] = *(const bf16x8*)&db_lds[(fn*16 + l15)*264 + kk*32 + kb];
        #pragma unroll
        for (int fn = 0; fn < 8; ++fn) {
          acc[0][fn] = __builtin_amdgcn_mfma_f32_16x16x32_bf16(aq[0][kk], b[fn], acc[0][fn], 0, 0, 0);
          acc[1][fn] = __builtin_amdgcn_mfma_f32_16x16x32_bf16(aq[1][kk], b[fn], acc[1][fn], 0, 0, 0);
        }
      }
    }
    __syncthreads();  // all waves done reading db tile before overwrite

    // ---- dump sims to LDS: C[row=q, col=db]; row=(lane>>4)*4+j, col=lane&15 ----
    {
      const int colb = lane & 15;
      const int rowb = (lane >> 4) << 2;
      #pragma unroll
      for (int fm = 0; fm < 2; ++fm)
        #pragma unroll
        for (int fn = 0; fn < 8; ++fn)
          #pragma unroll
          for (int j = 0; j < 4; ++j)
            sims[(wv*32 + fm*16 + rowb + j)*129 + fn*16 + colb] = acc[fm][fn][j];
    }
    __syncthreads();

    // ---- selection: 2 threads/query, 64 cols each, register top-16 ----
    {
      const int cb = half * 64;
      #pragma unroll 4
      for (int c = 0; c < 64; ++c) {
        const int colc = cb + c;
        const float v = sims[q_l*129 + colc];
        const int g = g0 + colc;
        if (v > minv && g < NDB) {
          #pragma unroll
          for (int i = 0; i < TK; ++i) if (i == minp) { tv[i] = v; ti[i] = (unsigned)g; }
          minv = tv[0]; minp = 0;
          #pragma unroll
          for (int i = 1; i < TK; ++i) if (tv[i] < minv) { minv = tv[i]; minp = i; }
        }
      }
    }
    __syncthreads();
  }

  // ---- write 16 candidates (exact top-16 of this thread's 2048-value set) ----
  {
    const int qg = mtile*MT + q_l;
    float*    pv = cand_val + ((size_t)qg*NCHUNK + cid)*32 + half*TK;
    unsigned* pi = cand_idx + ((size_t)qg*NCHUNK + cid)*32 + half*TK;
    #pragma unroll
    for (int i = 0; i < TK; ++i) { pv[i] = tv[i]; pi[i] = ti[i]; }
  }
}

// ---------------------------------------------------------------------------
// Stage 2: per-query merge of 1568 candidates -> exact top-16 -> vote
// grid QN, block 64 (1 wave)
// ---------------------------------------------------------------------------
__global__ __launch_bounds__(64) void merge_vote_kernel(
    const float* __restrict__ pdb,
    const float* __restrict__ cand_val, const unsigned* __restrict__ cand_idx,
    int* __restrict__ out_label, float* __restrict__ out_s)
{
  __shared__ float    cv[CAND_PER_Q];
  __shared__ unsigned ci[CAND_PER_Q];
  const int q    = (int)blockIdx.x;
  const int lane = (int)threadIdx.x;

  for (int j = lane; j < CAND_PER_Q; j += 64) {
    cv[j] = cand_val[(size_t)q*CAND_PER_Q + j];
    ci[j] = cand_idx[(size_t)q*CAND_PER_Q + j];
  }
  __syncthreads();

  float topv[TK]; int topid[TK];
  #pragma unroll
  for (int r = 0; r < TK; ++r) {
    float bv = NEGF; int bp = -1;
    for (int j = lane; j < CAND_PER_Q; j += 64) {
      const float v = cv[j];
      if (v > bv) { bv = v; bp = j; }
    }
    #pragma unroll
    for (int off = 32; off >= 1; off >>= 1) {
      const float ov = __shfl_xor(bv, off);
      const int   op = __shfl_xor(bp, off);
      if (ov > bv || (ov == bv && ((unsigned)op < (unsigned)bp))) { bv = ov; bp = op; }
    }
    topv[r] = bv;
    int id = -2;
    if (bp >= 0 && bv > NEGF) id = (int)pdb[(size_t)ci[bp]*PDBW + CDIM];
    topid[r] = id;
    if (lane == 0 && bp >= 0) cv[bp] = NEGF;
    __syncthreads();
  }

  if (lane == 0) {
    bool mk[TK];
    int nvalid = 0;
    #pragma unroll
    for (int i = 0; i < TK; ++i) {
      mk[i] = (topv[i] >= MIN_SIM_C) && (topid[i] >= 0);
      nvalid += mk[i] ? 1 : 0;
    }
    // majority = max class count, ties -> lowest class id (== jnp argmax semantics)
    int maj = 0, majid = 0x7fffffff;
    for (int i = 0; i < TK; ++i) {
      if (!mk[i]) continue;
      int c = 0;
      for (int j = 0; j < TK; ++j) c += (mk[j] && topid[j] == topid[i]) ? 1 : 0;
      if (c > maj || (c == maj && topid[i] < majid)) { maj = c; majid = topid[i]; }
    }
    const float ratio = (float)maj / fmaxf((float)nvalid, 1.0f);
    const bool valid = (maj > 0) && (ratio >= MIN_VOTES_C);
    const int label = valid ? majid : -1;
    float s = 0.f;
    #pragma unroll
    for (int i = 0; i < TK; ++i)
      if (mk[i] && topid[i] == label) s = fmaxf(s, topv[i]);
    out_label[q] = label;
    out_s[q]     = s;
  }
}

// ---------------------------------------------------------------------------
// Stage 3: overlap removal + final outputs
// remove[x] = exists y!=x: label_y==label_x>=0 && overlap>=0.5 && area_y<=area_x
// grid QN, block 64
// ---------------------------------------------------------------------------
__device__ __forceinline__ bool finitef(float v) {
  return ((__float_as_uint(v) >> 23) & 0xffu) != 0xffu;
}

__global__ __launch_bounds__(64) void finalize_kernel(
    const float* __restrict__ boxes, const int* __restrict__ labels,
    const float* __restrict__ svals, float* __restrict__ out)
{
  const int x    = (int)blockIdx.x;
  const int lane = (int)threadIdx.x;
  const int lx = labels[x];
  const float bx1 = boxes[x*4+0], by1 = boxes[x*4+1];
  const float bx2 = boxes[x*4+2], by2 = boxes[x*4+3];
  const float ax = (bx2 - bx1) * (by2 - by1);

  bool flag = false;
  if (lx >= 0) {
    for (int y = lane; y < QN; y += 64) {
      if (y == x) continue;
      if (labels[y] != lx) continue;
      const float c1 = boxes[y*4+0], c2 = boxes[y*4+1];
      const float c3 = boxes[y*4+2], c4 = boxes[y*4+3];
      const float ay = (c3 - c1) * (c4 - c2);
      const float xi1 = fmaxf(bx1, c1), yi1 = fmaxf(by1, c2);
      const float xi2 = fminf(bx2, c3), yi2 = fminf(by2, c4);
      const float inter = fmaxf(xi2 - xi1, 0.f) * fmaxf(yi2 - yi1, 0.f);
      const float asmall = fminf(ax, ay);
      const float ov = (asmall > 0.f) ? inter / fmaxf(asmall, 1e-12f) : 0.f;
      if (ov >= 0.5f && ay <= ax) flag = true;
    }
  }
  const bool removed = (__ballot(flag) != 0ull);
  const int label = removed ? -1 : lx;
  const float s = svals[x];
  const bool fin = finitef(s) && finitef(bx1) && finitef(by1) && finitef(bx2) && finitef(by2);
  const bool valid = (label >= 0) && fin;

  if (lane == 0) {
    out[4096 + x] = valid ? s : 0.f;
    out[5120 + x] = (float)(valid ? label : -1);
  }
  if (lane < 4) out[x*4 + lane] = boxes[x*4 + lane];
}

// ---------------------------------------------------------------------------
extern "C" void kernel_launch(void* const* d_in, const int* in_sizes, int n_in,
                              void* d_out, int out_size, void* d_ws, size_t ws_size,
                              hipStream_t stream)
{
  const float* boxes = (const float*)d_in[0];
  const float* qd    = (const float*)d_in[1];
  const float* pdb   = (const float*)d_in[2];
  float* out = (float*)d_out;

  // workspace layout: cand_val (6.42MB) | cand_idx (6.42MB) | labels | svals
  char* ws = (char*)d_ws;
  const size_t ncand = (size_t)QN * CAND_PER_Q;  // 1,605,632
  float*    cand_val = (float*)ws;
  unsigned* cand_idx = (unsigned*)(ws + ncand*4);
  int*      labels   = (int*)(ws + ncand*8);
  float*    svals    = (float*)(ws + ncand*8 + (size_t)QN*4);

  dim3 g1(NCHUNK, QN/MT);
  hipLaunchKernelGGL(sims_topk_kernel, g1, dim3(256), 0, stream,
                     qd, pdb, cand_val, cand_idx);
  hipLaunchKernelGGL(merge_vote_kernel, dim3(QN), dim3(64), 0, stream,
                     pdb, cand_val, cand_idx, labels, svals);
  hipLaunchKernelGGL(finalize_kernel, dim3(QN), dim3(64), 0, stream,
                     boxes, labels, svals, out);
}

// Round 2
// 1105.082 us; speedup vs baseline: 1.1931x; 1.1931x over previous
//
#include <hip/hip_runtime.h>
#include <hip/hip_bf16.h>

// ---------------- problem constants ----------------
#define QN 1024
#define NDB 200000
#define NDB_PAD 200064        // 1563 subtiles of 128 rows
#define PDBW 257
#define CDIM 256
#define TK 16
#define NEGF (-1e30f)
#define MIN_SIM_C 0.05f
#define MIN_VOTES_C 0.3f

// fast path: 64 chunks x 8 query-tiles = 512 blocks (2 clean CU-waves)
#define NCHUNK2 64
#define CPQ2 (NCHUNK2*32)     // 2048 candidates per query
// fallback (round-1) path
#define NCHUNK1 49
#define CPQ1 (NCHUNK1*32)     // 1568

typedef __attribute__((ext_vector_type(8))) short bf16x8;
typedef __attribute__((ext_vector_type(4))) float f32x4;

__device__ __forceinline__ short f2bf(float f) {
  union { float f; unsigned u; } x; x.f = f;
  unsigned u = x.u;
  return (short)((u + 0x7fffu + ((u >> 16) & 1u)) >> 16);  // RNE
}

__device__ __forceinline__ void async_copy16(const void* gp, void* lp) {
  __builtin_amdgcn_global_load_lds(
      (__attribute__((address_space(1))) void*)gp,
      (__attribute__((address_space(3))) void*)lp, 16, 0, 0);
}

// ---------------------------------------------------------------------------
// Kernel 0 (fast path): pdb fp32 -> bf16, row-swizzled (elem c -> c^((r&7)<<3)),
// zero-pad rows [NDB, NDB_PAD). One wave per row, lane covers 4 elems.
// ---------------------------------------------------------------------------
__global__ __launch_bounds__(256) void convert_db_kernel(
    const float* __restrict__ pdb, unsigned long long* __restrict__ dbb)
{
  const int wv = (int)threadIdx.x >> 6, lane = (int)threadIdx.x & 63;
  for (int r = (int)blockIdx.x*4 + wv; r < NDB_PAD; r += (int)gridDim.x*4) {
    const int c  = lane << 2;
    const int cs = c ^ ((r & 7) << 3);   // swizzle 8-elem blocks, keeps 4-alignment
    unsigned long long pack = 0ull;
    if (r < NDB) {
      const float* p = pdb + (size_t)r*PDBW + c;
      unsigned long long b0 = (unsigned short)f2bf(p[0]);
      unsigned long long b1 = (unsigned short)f2bf(p[1]);
      unsigned long long b2 = (unsigned short)f2bf(p[2]);
      unsigned long long b3 = (unsigned short)f2bf(p[3]);
      pack = b0 | (b1 << 16) | (b2 << 32) | (b3 << 48);
    }
    *(unsigned long long*)((char*)dbb + (size_t)r*512 + (cs << 1)) = pack;
  }
}

// ---------------------------------------------------------------------------
// Kernel 1 (fast path): bf16 MFMA sims + fused per-chunk top-16.
// grid (64, 8), 256 threads (4 waves x 32 queries). Per subtile (128 db rows):
//   global_load_lds stage (async, overlapped) | MFMA | wave-local dump+select.
// 2 barriers per subtile. LDS: db 64KB (swizzled) + per-wave sims col-major
// [128 cols][33] f32.
// ---------------------------------------------------------------------------
__global__ __launch_bounds__(256, 1) void sims_topk2_kernel(
    const float* __restrict__ qd, const unsigned long long* __restrict__ dbb,
    float* __restrict__ cand_val, unsigned int* __restrict__ cand_idx)
{
  __shared__ __align__(16) short db_lds[128 * 256];     // 65536 B
  __shared__ __align__(16) float simsbuf[4][128 * 33];  // 67584 B

  const int tid  = (int)threadIdx.x;
  const int lane = tid & 63;
  const int wv   = tid >> 6;
  const int cid   = (int)blockIdx.x;
  const int mtile = (int)blockIdx.y;
  // chunks 0..26 have 25 subtiles, 27..63 have 24 (covers NDB_PAD exactly)
  const int nsub = 24 + (cid < 27 ? 1 : 0);
  const int row0 = (24*cid + (cid < 27 ? cid : 27)) << 7;

  float* simw = simsbuf[wv];

  // ---- Q fragments (fp32 -> bf16, once per block) ----
  bf16x8 aq[2][8];
  {
    const int l15 = lane & 15;
    const int kb  = (lane >> 4) << 3;
    #pragma unroll
    for (int fm = 0; fm < 2; ++fm) {
      const int row = mtile*128 + wv*32 + fm*16 + l15;
      #pragma unroll
      for (int kk = 0; kk < 8; ++kk) {
        const float* p = qd + (size_t)row*CDIM + kk*32 + kb;
        float4 x0 = *(const float4*)p;
        float4 x1 = *(const float4*)(p + 4);
        bf16x8 a;
        a[0]=f2bf(x0.x); a[1]=f2bf(x0.y); a[2]=f2bf(x0.z); a[3]=f2bf(x0.w);
        a[4]=f2bf(x1.x); a[5]=f2bf(x1.y); a[6]=f2bf(x1.z); a[7]=f2bf(x1.w);
        aq[fm][kk] = a;
      }
    }
  }

  // top-16 state: wave-local query qsl = lane>>1, column half hf = lane&1
  float    tv[TK];
  unsigned ti[TK];
  #pragma unroll
  for (int i = 0; i < TK; ++i) { tv[i] = NEGF; ti[i] = 0u; }
  float minv = NEGF; int minp = 0;
  const int qsl = lane >> 1, hf = lane & 1;

  const char* dbbase = (const char*)dbb;
  // prologue: stage subtile 0 (each wave copies its 16KB quarter, linearly)
  {
    const char* src = dbbase + (size_t)row0*512 + wv*16384 + lane*16;
    char* dst = (char*)db_lds + wv*16384;
    #pragma unroll
    for (int j = 0; j < 16; ++j) async_copy16(src + j*1024, dst + j*1024);
  }
  __syncthreads();  // drains vmcnt(0): tile 0 resident

  for (int s = 0; s < nsub; ++s) {
    // ---- MFMA: 32q x 128db, K=256, swizzled b-frag reads ----
    f32x4 acc[2][8];
    #pragma unroll
    for (int fm = 0; fm < 2; ++fm)
      #pragma unroll
      for (int fn = 0; fn < 8; ++fn)
        acc[fm][fn] = (f32x4){0.f, 0.f, 0.f, 0.f};
    {
      const int l15  = lane & 15;
      const int egrp = lane >> 4;
      const int swz  = lane & 7;      // == R&7 for all fn
      #pragma unroll
      for (int kk = 0; kk < 8; ++kk) {
        const int e = (kk*4 + egrp) ^ swz;
        bf16x8 b[8];
        #pragma unroll
        for (int fn = 0; fn < 8; ++fn)
          b[fn] = *(const bf16x8*)((const char*)db_lds + (fn*16 + l15)*512 + e*16);
        #pragma unroll
        for (int fn = 0; fn < 8; ++fn) {
          acc[0][fn] = __builtin_amdgcn_mfma_f32_16x16x32_bf16(aq[0][kk], b[fn], acc[0][fn], 0, 0, 0);
          acc[1][fn] = __builtin_amdgcn_mfma_f32_16x16x32_bf16(aq[1][kk], b[fn], acc[1][fn], 0, 0, 0);
        }
      }
    }
    __syncthreads();  // all waves finished reading db_lds

    // issue async stage of next tile NOW; latency hides under dump+select
    if (s + 1 < nsub) {
      const char* src = dbbase + (size_t)(row0 + (s+1)*128)*512 + wv*16384 + lane*16;
      char* dst = (char*)db_lds + wv*16384;
      #pragma unroll
      for (int j = 0; j < 16; ++j) async_copy16(src + j*1024, dst + j*1024);
    }

    // ---- wave-local dump, col-major [col][q] stride 33 (conflict-free) ----
    {
      const int colb = lane & 15, rowb = (lane >> 4) << 2;
      #pragma unroll
      for (int fm = 0; fm < 2; ++fm)
        #pragma unroll
        for (int fn = 0; fn < 8; ++fn) {
          const int cb33 = (fn*16 + colb)*33 + fm*16 + rowb;
          #pragma unroll
          for (int j = 0; j < 4; ++j)
            simw[cb33 + j] = acc[fm][fn][j];
        }
    }

    // ---- wave-local select: 2 lanes/query, 64 cols each ----
    {
      const int g0s = row0 + s*128 + hf*64;
      const float* sp = simw + (hf*64)*33 + qsl;
      #pragma unroll 8
      for (int c = 0; c < 64; ++c) {
        const float v = sp[c*33];
        const int g = g0s + c;
        if (v > minv && g < NDB) {
          #pragma unroll
          for (int i = 0; i < TK; ++i) if (i == minp) { tv[i] = v; ti[i] = (unsigned)g; }
          minv = tv[0]; minp = 0;
          #pragma unroll
          for (int i = 1; i < TK; ++i) if (tv[i] < minv) { minv = tv[i]; minp = i; }
        }
      }
    }
    __syncthreads();  // drains vmcnt(0): next tile resident
  }

  // ---- write 16 candidates per (lane-half, query, chunk) ----
  {
    const int qg = mtile*128 + wv*32 + qsl;
    float*    pv = cand_val + (size_t)qg*CPQ2 + cid*32 + hf*TK;
    unsigned* pi = cand_idx + (size_t)qg*CPQ2 + cid*32 + hf*TK;
    #pragma unroll
    for (int i = 0; i < TK; ++i) { pv[i] = tv[i]; pi[i] = ti[i]; }
  }
}

// ---------------------------------------------------------------------------
// Fallback stage 1 (round-1, proven): on-the-fly conversion, 49x8 grid
// ---------------------------------------------------------------------------
__global__ __launch_bounds__(256, 2) void sims_topk1_kernel(
    const float* __restrict__ qd, const float* __restrict__ pdb,
    float* __restrict__ cand_val, unsigned int* __restrict__ cand_idx)
{
  __shared__ __align__(16) short db_lds[128 * 264];
  float* sims = (float*)db_lds;

  const int tid  = (int)threadIdx.x;
  const int lane = tid & 63;
  const int wv   = tid >> 6;
  const int cid   = (int)blockIdx.x;
  const int mtile = (int)blockIdx.y;

  bf16x8 aq[2][8];
  {
    const int l15 = lane & 15;
    const int kb  = (lane >> 4) << 3;
    #pragma unroll
    for (int fm = 0; fm < 2; ++fm) {
      const int row = mtile*128 + wv*32 + fm*16 + l15;
      #pragma unroll
      for (int kk = 0; kk < 8; ++kk) {
        const float* p = qd + (size_t)row*CDIM + kk*32 + kb;
        float4 x0 = *(const float4*)p;
        float4 x1 = *(const float4*)(p + 4);
        bf16x8 a;
        a[0]=f2bf(x0.x); a[1]=f2bf(x0.y); a[2]=f2bf(x0.z); a[3]=f2bf(x0.w);
        a[4]=f2bf(x1.x); a[5]=f2bf(x1.y); a[6]=f2bf(x1.z); a[7]=f2bf(x1.w);
        aq[fm][kk] = a;
      }
    }
  }

  float    tv[TK];
  unsigned ti[TK];
  #pragma unroll
  for (int i = 0; i < TK; ++i) { tv[i] = NEGF; ti[i] = 0u; }
  float minv = NEGF; int minp = 0;

  const int g0chunk = cid * 4096;
  const int q_l  = tid & 127;
  const int half = tid >> 7;

  for (int s = 0; s < 32; ++s) {
    const int g0 = g0chunk + s*128;
    {
      const int rb = tid >> 6;
      const int c4 = (tid & 63) << 2;
      for (int i = 0; i < 32; ++i) {
        const int rl = i*4 + rb;
        const int g  = g0 + rl;
        float v0, v1, v2, v3;
        if (g < NDB) {
          const float* p = pdb + (size_t)g*PDBW + c4;
          v0 = p[0]; v1 = p[1]; v2 = p[2]; v3 = p[3];
        } else { v0 = v1 = v2 = v3 = 0.f; }
        short* d = &db_lds[rl*264 + c4];
        d[0]=f2bf(v0); d[1]=f2bf(v1); d[2]=f2bf(v2); d[3]=f2bf(v3);
      }
    }
    __syncthreads();

    f32x4 acc[2][8];
    #pragma unroll
    for (int fm = 0; fm < 2; ++fm)
      #pragma unroll
      for (int fn = 0; fn < 8; ++fn)
        acc[fm][fn] = (f32x4){0.f, 0.f, 0.f, 0.f};
    {
      const int l15 = lane & 15;
      const int kb  = (lane >> 4) << 3;
      #pragma unroll
      for (int kk = 0; kk < 8; ++kk) {
        bf16x8 b[8];
        #pragma unroll
        for (int fn = 0; fn < 8; ++fn)
          b[fn] = *(const bf16x8*)&db_lds[(fn*16 + l15)*264 + kk*32 + kb];
        #pragma unroll
        for (int fn = 0; fn < 8; ++fn) {
          acc[0][fn] = __builtin_amdgcn_mfma_f32_16x16x32_bf16(aq[0][kk], b[fn], acc[0][fn], 0, 0, 0);
          acc[1][fn] = __builtin_amdgcn_mfma_f32_16x16x32_bf16(aq[1][kk], b[fn], acc[1][fn], 0, 0, 0);
        }
      }
    }
    __syncthreads();

    {
      const int colb = lane & 15;
      const int rowb = (lane >> 4) << 2;
      #pragma unroll
      for (int fm = 0; fm < 2; ++fm)
        #pragma unroll
        for (int fn = 0; fn < 8; ++fn)
          #pragma unroll
          for (int j = 0; j < 4; ++j)
            sims[(wv*32 + fm*16 + rowb + j)*129 + fn*16 + colb] = acc[fm][fn][j];
    }
    __syncthreads();

    {
      const int cb = half * 64;
      #pragma unroll 4
      for (int c = 0; c < 64; ++c) {
        const int colc = cb + c;
        const float v = sims[q_l*129 + colc];
        const int g = g0 + colc;
        if (v > minv && g < NDB) {
          #pragma unroll
          for (int i = 0; i < TK; ++i) if (i == minp) { tv[i] = v; ti[i] = (unsigned)g; }
          minv = tv[0]; minp = 0;
          #pragma unroll
          for (int i = 1; i < TK; ++i) if (tv[i] < minv) { minv = tv[i]; minp = i; }
        }
      }
    }
    __syncthreads();
  }

  {
    const int qg = mtile*128 + q_l;
    float*    pv = cand_val + ((size_t)qg*NCHUNK1 + cid)*32 + half*TK;
    unsigned* pi = cand_idx + ((size_t)qg*NCHUNK1 + cid)*32 + half*TK;
    #pragma unroll
    for (int i = 0; i < TK; ++i) { pv[i] = tv[i]; pi[i] = ti[i]; }
  }
}

// ---------------------------------------------------------------------------
// Stage 2: per-query merge of candidates -> exact top-16 -> vote
// ---------------------------------------------------------------------------
template<int CPQ>
__global__ __launch_bounds__(64) void merge_vote_kernel(
    const float* __restrict__ pdb,
    const float* __restrict__ cand_val, const unsigned* __restrict__ cand_idx,
    int* __restrict__ out_label, float* __restrict__ out_s)
{
  __shared__ float    cv[CPQ];
  __shared__ unsigned ci[CPQ];
  const int q    = (int)blockIdx.x;
  const int lane = (int)threadIdx.x;

  for (int j = lane; j < CPQ; j += 64) {
    cv[j] = cand_val[(size_t)q*CPQ + j];
    ci[j] = cand_idx[(size_t)q*CPQ + j];
  }
  __syncthreads();

  float topv[TK]; int topid[TK];
  #pragma unroll
  for (int r = 0; r < TK; ++r) {
    float bv = NEGF; int bp = -1;
    for (int j = lane; j < CPQ; j += 64) {
      const float v = cv[j];
      if (v > bv) { bv = v; bp = j; }
    }
    #pragma unroll
    for (int off = 32; off >= 1; off >>= 1) {
      const float ov = __shfl_xor(bv, off);
      const int   op = __shfl_xor(bp, off);
      if (ov > bv || (ov == bv && ((unsigned)op < (unsigned)bp))) { bv = ov; bp = op; }
    }
    topv[r] = bv;
    int id = -2;
    if (bp >= 0 && bv > NEGF) id = (int)pdb[(size_t)ci[bp]*PDBW + CDIM];
    topid[r] = id;
    if (lane == 0 && bp >= 0) cv[bp] = NEGF;
    __syncthreads();
  }

  if (lane == 0) {
    bool mk[TK];
    int nvalid = 0;
    #pragma unroll
    for (int i = 0; i < TK; ++i) {
      mk[i] = (topv[i] >= MIN_SIM_C) && (topid[i] >= 0);
      nvalid += mk[i] ? 1 : 0;
    }
    int maj = 0, majid = 0x7fffffff;
    for (int i = 0; i < TK; ++i) {
      if (!mk[i]) continue;
      int c = 0;
      for (int j = 0; j < TK; ++j) c += (mk[j] && topid[j] == topid[i]) ? 1 : 0;
      if (c > maj || (c == maj && topid[i] < majid)) { maj = c; majid = topid[i]; }
    }
    const float ratio = (float)maj / fmaxf((float)nvalid, 1.0f);
    const bool valid = (maj > 0) && (ratio >= MIN_VOTES_C);
    const int label = valid ? majid : -1;
    float s = 0.f;
    #pragma unroll
    for (int i = 0; i < TK; ++i)
      if (mk[i] && topid[i] == label) s = fmaxf(s, topv[i]);
    out_label[q] = label;
    out_s[q]     = s;
  }
}

// ---------------------------------------------------------------------------
// Stage 3: overlap removal + final outputs
// ---------------------------------------------------------------------------
__device__ __forceinline__ bool finitef(float v) {
  return ((__float_as_uint(v) >> 23) & 0xffu) != 0xffu;
}

__global__ __launch_bounds__(64) void finalize_kernel(
    const float* __restrict__ boxes, const int* __restrict__ labels,
    const float* __restrict__ svals, float* __restrict__ out)
{
  const int x    = (int)blockIdx.x;
  const int lane = (int)threadIdx.x;
  const int lx = labels[x];
  const float bx1 = boxes[x*4+0], by1 = boxes[x*4+1];
  const float bx2 = boxes[x*4+2], by2 = boxes[x*4+3];
  const float ax = (bx2 - bx1) * (by2 - by1);

  bool flag = false;
  if (lx >= 0) {
    for (int y = lane; y < QN; y += 64) {
      if (y == x) continue;
      if (labels[y] != lx) continue;
      const float c1 = boxes[y*4+0], c2 = boxes[y*4+1];
      const float c3 = boxes[y*4+2], c4 = boxes[y*4+3];
      const float ay = (c3 - c1) * (c4 - c2);
      const float xi1 = fmaxf(bx1, c1), yi1 = fmaxf(by1, c2);
      const float xi2 = fminf(bx2, c3), yi2 = fminf(by2, c4);
      const float inter = fmaxf(xi2 - xi1, 0.f) * fmaxf(yi2 - yi1, 0.f);
      const float asmall = fminf(ax, ay);
      const float ov = (asmall > 0.f) ? inter / fmaxf(asmall, 1e-12f) : 0.f;
      if (ov >= 0.5f && ay <= ax) flag = true;
    }
  }
  const bool removed = (__ballot(flag) != 0ull);
  const int label = removed ? -1 : lx;
  const float s = svals[x];
  const bool fin = finitef(s) && finitef(bx1) && finitef(by1) && finitef(bx2) && finitef(by2);
  const bool valid = (label >= 0) && fin;

  if (lane == 0) {
    out[4096 + x] = valid ? s : 0.f;
    out[5120 + x] = (float)(valid ? label : -1);
  }
  if (lane < 4) out[x*4 + lane] = boxes[x*4 + lane];
}

// ---------------------------------------------------------------------------
extern "C" void kernel_launch(void* const* d_in, const int* in_sizes, int n_in,
                              void* d_out, int out_size, void* d_ws, size_t ws_size,
                              hipStream_t stream)
{
  const float* boxes = (const float*)d_in[0];
  const float* qd    = (const float*)d_in[1];
  const float* pdb   = (const float*)d_in[2];
  float* out = (float*)d_out;
  char* ws = (char*)d_ws;

  const size_t db_bytes = (size_t)NDB_PAD * 512;      // 102,432,768
  const size_t n2 = (size_t)QN * CPQ2;                // 2,097,152
  const size_t need = db_bytes + n2*8 + (size_t)QN*8;

  if (ws_size >= need) {
    // fast path: pre-converted swizzled bf16 db
    unsigned long long* dbb = (unsigned long long*)ws;
    float*    cand_val = (float*)(ws + db_bytes);
    unsigned* cand_idx = (unsigned*)(ws + db_bytes + n2*4);
    int*      labels   = (int*)(ws + db_bytes + n2*8);
    float*    svals    = (float*)(ws + db_bytes + n2*8 + (size_t)QN*4);

    hipLaunchKernelGGL(convert_db_kernel, dim3(2048), dim3(256), 0, stream, pdb, dbb);
    hipLaunchKernelGGL(sims_topk2_kernel, dim3(NCHUNK2, 8), dim3(256), 0, stream,
                       qd, dbb, cand_val, cand_idx);
    hipLaunchKernelGGL((merge_vote_kernel<CPQ2>), dim3(QN), dim3(64), 0, stream,
                       pdb, cand_val, cand_idx, labels, svals);
    hipLaunchKernelGGL(finalize_kernel, dim3(QN), dim3(64), 0, stream,
                       boxes, labels, svals, out);
  } else {
    // fallback: round-1 path (12.9 MB ws)
    const size_t n1 = (size_t)QN * CPQ1;
    float*    cand_val = (float*)ws;
    unsigned* cand_idx = (unsigned*)(ws + n1*4);
    int*      labels   = (int*)(ws + n1*8);
    float*    svals    = (float*)(ws + n1*8 + (size_t)QN*4);

    hipLaunchKernelGGL(sims_topk1_kernel, dim3(NCHUNK1, 8), dim3(256), 0, stream,
                       qd, pdb, cand_val, cand_idx);
    hipLaunchKernelGGL((merge_vote_kernel<CPQ1>), dim3(QN), dim3(64), 0, stream,
                       pdb, cand_val, cand_idx, labels, svals);
    hipLaunchKernelGGL(finalize_kernel, dim3(QN), dim3(64), 0, stream,
                       boxes, labels, svals, out);
  }
}

// Round 3
// 214.738 us; speedup vs baseline: 6.1398x; 5.1462x over previous
//
#include <hip/hip_runtime.h>
#include <hip/hip_bf16.h>

// ---------------- problem constants ----------------
#define QN 1024
#define NDB 200000
#define NDB_PAD 200064        // 3126 subtiles of 64 rows
#define PDBW 257
#define CDIM 256
#define TK 16
#define NEGF (-1e30f)
#define MIN_SIM_C 0.05f
#define MIN_VOTES_C 0.3f

// fast path: 64 chunks x 8 query-tiles; survivor filter
#define NCH 64
#define THETA 0.19f           // P(sim>THETA)=1.18e-3; true 16th-best ~0.236 (12 sigma margin)
#define CAPQ 24               // per-(query,chunk) survivor cap (lambda=3.7, P(overflow)~1e-8)
// fallback (round-1, proven) path
#define NCHUNK1 49
#define CPQ1 (NCHUNK1*32)

typedef __attribute__((ext_vector_type(8))) short bf16x8;
typedef __attribute__((ext_vector_type(4))) float f32x4;

__device__ __forceinline__ short f2bf(float f) {
  union { float f; unsigned u; } x; x.f = f;
  unsigned u = x.u;
  return (short)((u + 0x7fffu + ((u >> 16) & 1u)) >> 16);  // RNE
}

__device__ __forceinline__ void async_copy16(const void* gp, void* lp) {
  __builtin_amdgcn_global_load_lds(
      (__attribute__((address_space(1))) void*)gp,
      (__attribute__((address_space(3))) void*)lp, 16, 0, 0);
}

// ---------------------------------------------------------------------------
// Kernel 0: pdb fp32 -> bf16, row-swizzled (16B block e -> e^(r&7)), zero-pad.
// ---------------------------------------------------------------------------
__global__ __launch_bounds__(256) void convert_db_kernel(
    const float* __restrict__ pdb, unsigned long long* __restrict__ dbb)
{
  const int wv = (int)threadIdx.x >> 6, lane = (int)threadIdx.x & 63;
  for (int r = (int)blockIdx.x*4 + wv; r < NDB_PAD; r += (int)gridDim.x*4) {
    const int c  = lane << 2;
    const int cs = c ^ ((r & 7) << 3);
    unsigned long long pack = 0ull;
    if (r < NDB) {
      const float* p = pdb + (size_t)r*PDBW + c;
      unsigned long long b0 = (unsigned short)f2bf(p[0]);
      unsigned long long b1 = (unsigned short)f2bf(p[1]);
      unsigned long long b2 = (unsigned short)f2bf(p[2]);
      unsigned long long b3 = (unsigned short)f2bf(p[3]);
      pack = b0 | (b1 << 16) | (b2 << 32) | (b3 << 48);
    }
    *(unsigned long long*)((char*)dbb + (size_t)r*512 + (cs << 1)) = pack;
  }
}

// ---------------------------------------------------------------------------
// Kernel 1: MFMA sims + register-level theta-filter + LDS survivor append.
// grid (64, 8), 256 thr (4 waves x 32 queries). Subtile = 64 db rows (32KB).
// No sims transpose, no per-value top-k. LDS 57.9KB -> 2 blocks/CU.
// ---------------------------------------------------------------------------
__global__ __launch_bounds__(256, 2) void sims_filter_kernel(
    const float* __restrict__ qd, const unsigned long long* __restrict__ dbb,
    unsigned long long* __restrict__ seg_g, unsigned int* __restrict__ cnt_g)
{
  __shared__ __align__(16) short db_lds[64 * 256];       // 32768 B
  __shared__ unsigned seg_lds[4][32][CAPQ][2];           // 24576 B
  __shared__ int lcnt[4][32];                            // 512 B

  const int tid  = (int)threadIdx.x;
  const int lane = tid & 63;
  const int wv   = tid >> 6;
  const int cid   = (int)blockIdx.x;
  const int mtile = (int)blockIdx.y;
  // chunks 0..53 have 49 subtiles, 54..63 have 48 (covers 3126 subtiles)
  const int nsub = 48 + (cid < 54 ? 1 : 0);
  const int row0 = (48*cid + (cid < 54 ? cid : 54)) << 6;

  if (tid < 128) lcnt[tid >> 5][tid & 31] = 0;

  // ---- Q fragments (fp32 -> bf16, once per block) ----
  bf16x8 aq[2][8];
  {
    const int l15 = lane & 15;
    const int kb  = (lane >> 4) << 3;
    #pragma unroll
    for (int fm = 0; fm < 2; ++fm) {
      const int row = mtile*128 + wv*32 + fm*16 + l15;
      #pragma unroll
      for (int kk = 0; kk < 8; ++kk) {
        const float* p = qd + (size_t)row*CDIM + kk*32 + kb;
        float4 x0 = *(const float4*)p;
        float4 x1 = *(const float4*)(p + 4);
        bf16x8 a;
        a[0]=f2bf(x0.x); a[1]=f2bf(x0.y); a[2]=f2bf(x0.z); a[3]=f2bf(x0.w);
        a[4]=f2bf(x1.x); a[5]=f2bf(x1.y); a[6]=f2bf(x1.z); a[7]=f2bf(x1.w);
        aq[fm][kk] = a;
      }
    }
  }

  const char* dbbase = (const char*)dbb;
  // prologue: stage subtile 0 (each wave: 8KB linear)
  {
    const char* src = dbbase + (size_t)row0*512 + wv*8192 + lane*16;
    char* dst = (char*)db_lds + wv*8192;
    #pragma unroll
    for (int j = 0; j < 8; ++j) async_copy16(src + j*1024, dst + j*1024);
  }
  __syncthreads();

  const int l15  = lane & 15;
  const int egrp = lane >> 4;
  const int swz  = lane & 7;
  const int rowb = (lane >> 4) << 2;
  const int colb = lane & 15;

  for (int s = 0; s < nsub; ++s) {
    // ---- MFMA: 32q x 64db, K=256 ----
    f32x4 acc[2][4];
    #pragma unroll
    for (int fm = 0; fm < 2; ++fm)
      #pragma unroll
      for (int fn = 0; fn < 4; ++fn)
        acc[fm][fn] = (f32x4){0.f, 0.f, 0.f, 0.f};
    #pragma unroll
    for (int kk = 0; kk < 8; ++kk) {
      const int e = (kk*4 + egrp) ^ swz;
      bf16x8 b[4];
      #pragma unroll
      for (int fn = 0; fn < 4; ++fn)
        b[fn] = *(const bf16x8*)((const char*)db_lds + (fn*16 + l15)*512 + e*16);
      #pragma unroll
      for (int fn = 0; fn < 4; ++fn) {
        acc[0][fn] = __builtin_amdgcn_mfma_f32_16x16x32_bf16(aq[0][kk], b[fn], acc[0][fn], 0, 0, 0);
        acc[1][fn] = __builtin_amdgcn_mfma_f32_16x16x32_bf16(aq[1][kk], b[fn], acc[1][fn], 0, 0, 0);
      }
    }
    __syncthreads();  // all waves done reading db_lds

    // stage next tile (DMA overlaps the filter below)
    if (s + 1 < nsub) {
      const char* src = dbbase + (size_t)(row0 + (s+1)*64)*512 + wv*8192 + lane*16;
      char* dst = (char*)db_lds + wv*8192;
      #pragma unroll
      for (int j = 0; j < 8; ++j) async_copy16(src + j*1024, dst + j*1024);
    }

    // ---- theta-filter directly on fragments; append survivors ----
    {
      const int idxbase = row0 + s*64;
      #pragma unroll
      for (int fm = 0; fm < 2; ++fm)
        #pragma unroll
        for (int fn = 0; fn < 4; ++fn) {
          const f32x4 a = acc[fm][fn];
          const float m = fmaxf(fmaxf(a[0], a[1]), fmaxf(a[2], a[3]));
          if (m > THETA) {                       // rare (~7% of groups wave-wide)
            #pragma unroll
            for (int j = 0; j < 4; ++j) {
              if (a[j] > THETA) {
                const int ql = fm*16 + rowb + j;
                const int slot = atomicAdd(&lcnt[wv][ql], 1);
                if (slot < CAPQ) {
                  seg_lds[wv][ql][slot][0] = __float_as_uint(a[j]);
                  seg_lds[wv][ql][slot][1] = (unsigned)(idxbase + fn*16 + colb);
                }
              }
            }
          }
        }
    }
    __syncthreads();  // drains vmcnt: next tile resident; appends visible
  }

  // ---- flush survivor lists to global ----
  {
    const int ql2 = lane >> 1, hf = lane & 1;
    const int cnt = lcnt[wv][ql2];
    const int qg = mtile*128 + wv*32 + ql2;
    if (hf == 0) cnt_g[qg*NCH + cid] = (unsigned)cnt;
    const int nc = min(cnt, CAPQ);
    unsigned long long* dst = seg_g + (size_t)(qg*NCH + cid)*CAPQ;
    for (int j = hf; j < nc; j += 2) {
      unsigned long long lo = seg_lds[wv][ql2][j][0];
      unsigned long long hi = seg_lds[wv][ql2][j][1];
      dst[j] = lo | (hi << 32);
    }
  }
}

// ---------------------------------------------------------------------------
// Kernel 2: per-query gather of survivors -> exact top-16 -> vote.
// Self-check: overflow or <16 survivors -> set flag (triggers fallback).
// ---------------------------------------------------------------------------
__global__ __launch_bounds__(64) void gather_vote_kernel(
    const float* __restrict__ pdb,
    const unsigned long long* __restrict__ seg_g, const unsigned* __restrict__ cnt_g,
    int* __restrict__ out_label, float* __restrict__ out_s, int* __restrict__ flag)
{
  __shared__ float    cv[NCH*CAPQ];
  __shared__ unsigned ci[NCH*CAPQ];
  const int q    = (int)blockIdx.x;
  const int lane = (int)threadIdx.x;   // lane == chunk id (64)

  const int cnt = (int)cnt_g[q*NCH + lane];
  const bool over = cnt > CAPQ;
  const int nc = min(cnt, CAPQ);
  int tot = nc;
  #pragma unroll
  for (int off = 32; off >= 1; off >>= 1) tot += __shfl_xor(tot, off);

  const unsigned long long* src = seg_g + (size_t)(q*NCH + lane)*CAPQ;
  for (int j = 0; j < CAPQ; ++j) {
    float v = NEGF; unsigned idx = 0u;
    if (j < nc) {
      const unsigned long long e = src[j];
      v = __uint_as_float((unsigned)e);
      idx = (unsigned)(e >> 32);
    }
    cv[lane*CAPQ + j] = v;
    ci[lane*CAPQ + j] = idx;
  }
  __syncthreads();

  float topv[TK]; int topid[TK];
  #pragma unroll
  for (int r = 0; r < TK; ++r) {
    float bv = NEGF; int bp = -1;
    #pragma unroll 4
    for (int j = 0; j < CAPQ; ++j) {
      const float v = cv[lane*CAPQ + j];
      const int p = lane*CAPQ + j;
      if (v > bv) { bv = v; bp = p; }
    }
    #pragma unroll
    for (int off = 32; off >= 1; off >>= 1) {
      const float ov = __shfl_xor(bv, off);
      const int   op = __shfl_xor(bp, off);
      if (ov > bv || (ov == bv && ((unsigned)op < (unsigned)bp))) { bv = ov; bp = op; }
    }
    topv[r] = bv;
    int id = -2;
    if (bp >= 0 && bv > NEGF) id = (int)pdb[(size_t)ci[bp]*PDBW + CDIM];
    topid[r] = id;
    if (lane == 0 && bp >= 0) cv[bp] = NEGF;
    __syncthreads();
  }

  if (lane == 0) {
    bool mk[TK];
    int nvalid = 0;
    #pragma unroll
    for (int i = 0; i < TK; ++i) {
      mk[i] = (topv[i] >= MIN_SIM_C) && (topid[i] >= 0);
      nvalid += mk[i] ? 1 : 0;
    }
    int maj = 0, majid = 0x7fffffff;
    for (int i = 0; i < TK; ++i) {
      if (!mk[i]) continue;
      int c = 0;
      for (int j = 0; j < TK; ++j) c += (mk[j] && topid[j] == topid[i]) ? 1 : 0;
      if (c > maj || (c == maj && topid[i] < majid)) { maj = c; majid = topid[i]; }
    }
    const float ratio = (float)maj / fmaxf((float)nvalid, 1.0f);
    const bool valid = (maj > 0) && (ratio >= MIN_VOTES_C);
    const int label = valid ? majid : -1;
    float s = 0.f;
    #pragma unroll
    for (int i = 0; i < TK; ++i)
      if (mk[i] && topid[i] == label) s = fmaxf(s, topv[i]);
    out_label[q] = label;
    out_s[q]     = s;
  }
  // exactness self-check (wave-uniform via ballot)
  const bool bad = (__ballot(over) != 0ull) || (tot < TK);
  if (lane == 0 && bad) atomicOr(flag, 1);
}

// ---------------------------------------------------------------------------
// Fallback stage 1 (round-1, proven): gated on flag (runs only if filter failed)
// ---------------------------------------------------------------------------
__global__ __launch_bounds__(256, 2) void sims_topk1_kernel(
    const float* __restrict__ qd, const float* __restrict__ pdb,
    float* __restrict__ cand_val, unsigned int* __restrict__ cand_idx,
    const int* __restrict__ gate)
{
  if (gate && *gate == 0) return;
  __shared__ __align__(16) short db_lds[128 * 264];
  float* sims = (float*)db_lds;

  const int tid  = (int)threadIdx.x;
  const int lane = tid & 63;
  const int wv   = tid >> 6;
  const int cid   = (int)blockIdx.x;
  const int mtile = (int)blockIdx.y;

  bf16x8 aq[2][8];
  {
    const int l15 = lane & 15;
    const int kb  = (lane >> 4) << 3;
    #pragma unroll
    for (int fm = 0; fm < 2; ++fm) {
      const int row = mtile*128 + wv*32 + fm*16 + l15;
      #pragma unroll
      for (int kk = 0; kk < 8; ++kk) {
        const float* p = qd + (size_t)row*CDIM + kk*32 + kb;
        float4 x0 = *(const float4*)p;
        float4 x1 = *(const float4*)(p + 4);
        bf16x8 a;
        a[0]=f2bf(x0.x); a[1]=f2bf(x0.y); a[2]=f2bf(x0.z); a[3]=f2bf(x0.w);
        a[4]=f2bf(x1.x); a[5]=f2bf(x1.y); a[6]=f2bf(x1.z); a[7]=f2bf(x1.w);
        aq[fm][kk] = a;
      }
    }
  }

  float    tv[TK];
  unsigned ti[TK];
  #pragma unroll
  for (int i = 0; i < TK; ++i) { tv[i] = NEGF; ti[i] = 0u; }
  float minv = NEGF; int minp = 0;

  const int g0chunk = cid * 4096;
  const int q_l  = tid & 127;
  const int half = tid >> 7;

  for (int s = 0; s < 32; ++s) {
    const int g0 = g0chunk + s*128;
    {
      const int rb = tid >> 6;
      const int c4 = (tid & 63) << 2;
      for (int i = 0; i < 32; ++i) {
        const int rl = i*4 + rb;
        const int g  = g0 + rl;
        float v0, v1, v2, v3;
        if (g < NDB) {
          const float* p = pdb + (size_t)g*PDBW + c4;
          v0 = p[0]; v1 = p[1]; v2 = p[2]; v3 = p[3];
        } else { v0 = v1 = v2 = v3 = 0.f; }
        short* d = &db_lds[rl*264 + c4];
        d[0]=f2bf(v0); d[1]=f2bf(v1); d[2]=f2bf(v2); d[3]=f2bf(v3);
      }
    }
    __syncthreads();

    f32x4 acc[2][8];
    #pragma unroll
    for (int fm = 0; fm < 2; ++fm)
      #pragma unroll
      for (int fn = 0; fn < 8; ++fn)
        acc[fm][fn] = (f32x4){0.f, 0.f, 0.f, 0.f};
    {
      const int l15 = lane & 15;
      const int kb  = (lane >> 4) << 3;
      #pragma unroll
      for (int kk = 0; kk < 8; ++kk) {
        bf16x8 b[8];
        #pragma unroll
        for (int fn = 0; fn < 8; ++fn)
          b[fn] = *(const bf16x8*)&db_lds[(fn*16 + l15)*264 + kk*32 + kb];
        #pragma unroll
        for (int fn = 0; fn < 8; ++fn) {
          acc[0][fn] = __builtin_amdgcn_mfma_f32_16x16x32_bf16(aq[0][kk], b[fn], acc[0][fn], 0, 0, 0);
          acc[1][fn] = __builtin_amdgcn_mfma_f32_16x16x32_bf16(aq[1][kk], b[fn], acc[1][fn], 0, 0, 0);
        }
      }
    }
    __syncthreads();

    {
      const int colb = lane & 15;
      const int rowb = (lane >> 4) << 2;
      #pragma unroll
      for (int fm = 0; fm < 2; ++fm)
        #pragma unroll
        for (int fn = 0; fn < 8; ++fn)
          #pragma unroll
          for (int j = 0; j < 4; ++j)
            sims[(wv*32 + fm*16 + rowb + j)*129 + fn*16 + colb] = acc[fm][fn][j];
    }
    __syncthreads();

    {
      const int cb = half * 64;
      #pragma unroll 4
      for (int c = 0; c < 64; ++c) {
        const int colc = cb + c;
        const float v = sims[q_l*129 + colc];
        const int g = g0 + colc;
        if (v > minv && g < NDB) {
          #pragma unroll
          for (int i = 0; i < TK; ++i) if (i == minp) { tv[i] = v; ti[i] = (unsigned)g; }
          minv = tv[0]; minp = 0;
          #pragma unroll
          for (int i = 1; i < TK; ++i) if (tv[i] < minv) { minv = tv[i]; minp = i; }
        }
      }
    }
    __syncthreads();
  }

  {
    const int qg = mtile*128 + q_l;
    float*    pv = cand_val + ((size_t)qg*NCHUNK1 + cid)*32 + half*TK;
    unsigned* pi = cand_idx + ((size_t)qg*NCHUNK1 + cid)*32 + half*TK;
    #pragma unroll
    for (int i = 0; i < TK; ++i) { pv[i] = tv[i]; pi[i] = ti[i]; }
  }
}

// ---------------------------------------------------------------------------
// Fallback stage 2 (round-1, proven): gated on flag
// ---------------------------------------------------------------------------
template<int CPQ>
__global__ __launch_bounds__(64) void merge_vote_kernel(
    const float* __restrict__ pdb,
    const float* __restrict__ cand_val, const unsigned* __restrict__ cand_idx,
    int* __restrict__ out_label, float* __restrict__ out_s,
    const int* __restrict__ gate)
{
  if (gate && *gate == 0) return;
  __shared__ float    cv[CPQ];
  __shared__ unsigned ci[CPQ];
  const int q    = (int)blockIdx.x;
  const int lane = (int)threadIdx.x;

  for (int j = lane; j < CPQ; j += 64) {
    cv[j] = cand_val[(size_t)q*CPQ + j];
    ci[j] = cand_idx[(size_t)q*CPQ + j];
  }
  __syncthreads();

  float topv[TK]; int topid[TK];
  #pragma unroll
  for (int r = 0; r < TK; ++r) {
    float bv = NEGF; int bp = -1;
    for (int j = lane; j < CPQ; j += 64) {
      const float v = cv[j];
      if (v > bv) { bv = v; bp = j; }
    }
    #pragma unroll
    for (int off = 32; off >= 1; off >>= 1) {
      const float ov = __shfl_xor(bv, off);
      const int   op = __shfl_xor(bp, off);
      if (ov > bv || (ov == bv && ((unsigned)op < (unsigned)bp))) { bv = ov; bp = op; }
    }
    topv[r] = bv;
    int id = -2;
    if (bp >= 0 && bv > NEGF) id = (int)pdb[(size_t)ci[bp]*PDBW + CDIM];
    topid[r] = id;
    if (lane == 0 && bp >= 0) cv[bp] = NEGF;
    __syncthreads();
  }

  if (lane == 0) {
    bool mk[TK];
    int nvalid = 0;
    #pragma unroll
    for (int i = 0; i < TK; ++i) {
      mk[i] = (topv[i] >= MIN_SIM_C) && (topid[i] >= 0);
      nvalid += mk[i] ? 1 : 0;
    }
    int maj = 0, majid = 0x7fffffff;
    for (int i = 0; i < TK; ++i) {
      if (!mk[i]) continue;
      int c = 0;
      for (int j = 0; j < TK; ++j) c += (mk[j] && topid[j] == topid[i]) ? 1 : 0;
      if (c > maj || (c == maj && topid[i] < majid)) { maj = c; majid = topid[i]; }
    }
    const float ratio = (float)maj / fmaxf((float)nvalid, 1.0f);
    const bool valid = (maj > 0) && (ratio >= MIN_VOTES_C);
    const int label = valid ? majid : -1;
    float s = 0.f;
    #pragma unroll
    for (int i = 0; i < TK; ++i)
      if (mk[i] && topid[i] == label) s = fmaxf(s, topv[i]);
    out_label[q] = label;
    out_s[q]     = s;
  }
}

// ---------------------------------------------------------------------------
// Stage 3: overlap removal + final outputs
// ---------------------------------------------------------------------------
__device__ __forceinline__ bool finitef(float v) {
  return ((__float_as_uint(v) >> 23) & 0xffu) != 0xffu;
}

__global__ __launch_bounds__(64) void finalize_kernel(
    const float* __restrict__ boxes, const int* __restrict__ labels,
    const float* __restrict__ svals, float* __restrict__ out)
{
  const int x    = (int)blockIdx.x;
  const int lane = (int)threadIdx.x;
  const int lx = labels[x];
  const float bx1 = boxes[x*4+0], by1 = boxes[x*4+1];
  const float bx2 = boxes[x*4+2], by2 = boxes[x*4+3];
  const float ax = (bx2 - bx1) * (by2 - by1);

  bool flag = false;
  if (lx >= 0) {
    for (int y = lane; y < QN; y += 64) {
      if (y == x) continue;
      if (labels[y] != lx) continue;
      const float c1 = boxes[y*4+0], c2 = boxes[y*4+1];
      const float c3 = boxes[y*4+2], c4 = boxes[y*4+3];
      const float ay = (c3 - c1) * (c4 - c2);
      const float xi1 = fmaxf(bx1, c1), yi1 = fmaxf(by1, c2);
      const float xi2 = fminf(bx2, c3), yi2 = fminf(by2, c4);
      const float inter = fmaxf(xi2 - xi1, 0.f) * fmaxf(yi2 - yi1, 0.f);
      const float asmall = fminf(ax, ay);
      const float ov = (asmall > 0.f) ? inter / fmaxf(asmall, 1e-12f) : 0.f;
      if (ov >= 0.5f && ay <= ax) flag = true;
    }
  }
  const bool removed = (__ballot(flag) != 0ull);
  const int label = removed ? -1 : lx;
  const float s = svals[x];
  const bool fin = finitef(s) && finitef(bx1) && finitef(by1) && finitef(bx2) && finitef(by2);
  const bool valid = (label >= 0) && fin;

  if (lane == 0) {
    out[4096 + x] = valid ? s : 0.f;
    out[5120 + x] = (float)(valid ? label : -1);
  }
  if (lane < 4) out[x*4 + lane] = boxes[x*4 + lane];
}

// ---------------------------------------------------------------------------
extern "C" void kernel_launch(void* const* d_in, const int* in_sizes, int n_in,
                              void* d_out, int out_size, void* d_ws, size_t ws_size,
                              hipStream_t stream)
{
  const float* boxes = (const float*)d_in[0];
  const float* qd    = (const float*)d_in[1];
  const float* pdb   = (const float*)d_in[2];
  float* out = (float*)d_out;
  char* ws = (char*)d_ws;

  const size_t db_bytes  = (size_t)NDB_PAD * 512;             // 102,432,768
  const size_t seg_bytes = (size_t)QN * NCH * CAPQ * 8;       // 12,582,912
  const size_t cnt_bytes = (size_t)QN * NCH * 4;              //    262,144
  const size_t c1_bytes  = (size_t)QN * CPQ1 * 8;             // 12,845,056 (fallback, aliases seg+cnt)
  const size_t A_bytes   = (seg_bytes + cnt_bytes > c1_bytes) ? seg_bytes + cnt_bytes : c1_bytes;
  const size_t need = db_bytes + A_bytes + (size_t)QN*8 + 64;

  if (ws_size >= need) {
    unsigned long long* dbb = (unsigned long long*)ws;
    char* A = ws + db_bytes;
    unsigned long long* seg_g = (unsigned long long*)A;
    unsigned*           cnt_g = (unsigned*)(A + seg_bytes);
    // fallback candidate arrays alias A (only used when flag fires)
    float*    cand_val = (float*)A;
    unsigned* cand_idx = (unsigned*)(A + (size_t)QN*CPQ1*4);
    int*      labels   = (int*)(ws + db_bytes + A_bytes);
    float*    svals    = (float*)(ws + db_bytes + A_bytes + (size_t)QN*4);
    int*      flag     = (int*)(ws + db_bytes + A_bytes + (size_t)QN*8);

    hipMemsetAsync(flag, 0, 4, stream);
    hipLaunchKernelGGL(convert_db_kernel, dim3(2048), dim3(256), 0, stream, pdb, dbb);
    hipLaunchKernelGGL(sims_filter_kernel, dim3(NCH, 8), dim3(256), 0, stream,
                       qd, dbb, seg_g, cnt_g);
    hipLaunchKernelGGL(gather_vote_kernel, dim3(QN), dim3(64), 0, stream,
                       pdb, seg_g, cnt_g, labels, svals, flag);
    // safety net: runs only if the statistical filter failed (flag != 0)
    hipLaunchKernelGGL(sims_topk1_kernel, dim3(NCHUNK1, 8), dim3(256), 0, stream,
                       qd, pdb, cand_val, cand_idx, flag);
    hipLaunchKernelGGL((merge_vote_kernel<CPQ1>), dim3(QN), dim3(64), 0, stream,
                       pdb, cand_val, cand_idx, labels, svals, flag);
    hipLaunchKernelGGL(finalize_kernel, dim3(QN), dim3(64), 0, stream,
                       boxes, labels, svals, out);
  } else {
    // small-ws fallback: full round-1 proven path
    const size_t n1 = (size_t)QN * CPQ1;
    float*    cand_val = (float*)ws;
    unsigned* cand_idx = (unsigned*)(ws + n1*4);
    int*      labels   = (int*)(ws + n1*8);
    float*    svals    = (float*)(ws + n1*8 + (size_t)QN*4);

    hipLaunchKernelGGL(sims_topk1_kernel, dim3(NCHUNK1, 8), dim3(256), 0, stream,
                       qd, pdb, cand_val, cand_idx, (const int*)nullptr);
    hipLaunchKernelGGL((merge_vote_kernel<CPQ1>), dim3(QN), dim3(64), 0, stream,
                       pdb, cand_val, cand_idx, labels, svals, (const int*)nullptr);
    hipLaunchKernelGGL(finalize_kernel, dim3(QN), dim3(64), 0, stream,
                       boxes, labels, svals, out);
  }
}